// Round 2
// baseline (178.812 us; speedup 1.0000x reference)
//
#include <hip/hip_runtime.h>

// Problem constants (from reference)
#define N_NODES 16384
#define D_EMB   128
#define LIST_CAP 1024   // max common neighbors (max degree ~200 incl. i==j case)

// Layout probe: the harness contract maps integer-kind inputs (incl. bool) to
// int32, but we guard against a byte-per-bool layout too. Scan the first
// 16384 words: int32-encoded 0/1 values give every word in {0,1}; byte-encoded
// rows (~524 one-bytes in 64KB at random byte offsets) give words >1 with
// probability 1 - 4^-524 ~= 1. flag: 1 => byte layout, 0 => int32 layout.
__global__ __launch_bounds__(256) void detect_layout_kernel(
    const unsigned int* __restrict__ words, int* __restrict__ flag)
{
    __shared__ int s_any;
    if (threadIdx.x == 0) s_any = 0;
    __syncthreads();
    int any = 0;
    for (int k = threadIdx.x; k < 16384; k += 256) {
        if (words[k] > 1u) any = 1;
    }
    if (any) atomicOr(&s_any, 1);
    __syncthreads();
    if (threadIdx.x == 0) *flag = s_any;
}

__global__ __launch_bounds__(256) void ncn_kernel(
    const int* __restrict__ links,            // [n_links][2] int32
    const void* __restrict__ adjv,            // [N_NODES][N_NODES] bool, int32 OR byte encoded
    const float* __restrict__ emb,            // [N_NODES][D_EMB] fp32
    float* __restrict__ out,                  // [n_links][2*D_EMB] fp32
    const int* __restrict__ flag,             // layout flag in d_ws (or null => assume bytes)
    int n_links)
{
    const int link = blockIdx.x;
    if (link >= n_links) return;

    const int i = links[2 * link];
    const int j = links[2 * link + 1];

    __shared__ int s_list[LIST_CAP];
    __shared__ int s_count;
    if (threadIdx.x == 0) s_count = 0;
    __syncthreads();

    const int byte_layout = flag ? flag[0] : 1;  // uniform branch across block

    if (byte_layout) {
        // Row = 16384 bytes = 1024 uint4 chunks; 256 threads -> 4 chunks each.
        const uint4* rowi = reinterpret_cast<const uint4*>(
            (const unsigned char*)adjv + (size_t)i * N_NODES);
        const uint4* rowj = reinterpret_cast<const uint4*>(
            (const unsigned char*)adjv + (size_t)j * N_NODES);
#pragma unroll
        for (int c = 0; c < 4; ++c) {
            const int idx = c * 256 + threadIdx.x;
            const uint4 a = rowi[idx];
            const uint4 b = rowj[idx];
            unsigned int m[4];
            m[0] = a.x & b.x; m[1] = a.y & b.y; m[2] = a.z & b.z; m[3] = a.w & b.w;
            if (m[0] | m[1] | m[2] | m[3]) {
                const int base = idx * 16;  // node index of chunk start
#pragma unroll
                for (int w = 0; w < 4; ++w) {
                    unsigned int v = m[w];
                    if (!v) continue;
#pragma unroll
                    for (int b8 = 0; b8 < 4; ++b8) {
                        if ((v >> (8 * b8)) & 0xFFu) {
                            int pos = atomicAdd(&s_count, 1);
                            if (pos < LIST_CAP) s_list[pos] = base + w * 4 + b8;
                        }
                    }
                }
            }
        }
    } else {
        // int32 per node: row = 16384 ints = 65536 B = 4096 uint4 chunks;
        // 256 threads -> 16 chunks each; each chunk covers 4 nodes.
        const uint4* rowi = reinterpret_cast<const uint4*>(
            (const int*)adjv + (size_t)i * N_NODES);
        const uint4* rowj = reinterpret_cast<const uint4*>(
            (const int*)adjv + (size_t)j * N_NODES);
#pragma unroll
        for (int c = 0; c < 16; ++c) {
            const int idx = c * 256 + threadIdx.x;
            const uint4 a = rowi[idx];
            const uint4 b = rowj[idx];
            const int base = idx * 4;
            if (a.x & b.x) { int p = atomicAdd(&s_count, 1); if (p < LIST_CAP) s_list[p] = base + 0; }
            if (a.y & b.y) { int p = atomicAdd(&s_count, 1); if (p < LIST_CAP) s_list[p] = base + 1; }
            if (a.z & b.z) { int p = atomicAdd(&s_count, 1); if (p < LIST_CAP) s_list[p] = base + 2; }
            if (a.w & b.w) { int p = atomicAdd(&s_count, 1); if (p < LIST_CAP) s_list[p] = base + 3; }
        }
    }
    __syncthreads();

    int count = s_count;
    if (count > LIST_CAP) count = LIST_CAP;

    // Epilogue: out row = [product(128) | cn_sum(128)]
    const int t = threadIdx.x;
    const size_t obase = (size_t)link * (2 * D_EMB);
    if (t < D_EMB) {
        const float ei = emb[(size_t)i * D_EMB + t];
        const float ej = emb[(size_t)j * D_EMB + t];
        out[obase + t] = ei * ej;
    } else {
        const int d = t - D_EMB;
        float s = 0.0f;
        for (int c = 0; c < count; ++c) {
            s += emb[(size_t)s_list[c] * D_EMB + d];
        }
        out[obase + D_EMB + d] = s;
    }
}

extern "C" void kernel_launch(void* const* d_in, const int* in_sizes, int n_in,
                              void* d_out, int out_size, void* d_ws, size_t ws_size,
                              hipStream_t stream) {
    const int* links = (const int*)d_in[0];     // int32 [n_links][2]
    const void* adj = d_in[1];                  // bool [N_NODES][N_NODES], encoding probed
    const float* emb = (const float*)d_in[2];   // fp32 [N_NODES][D_EMB]
    float* out = (float*)d_out;

    const int n_links = in_sizes[0] / 2;

    int* flag = (ws_size >= sizeof(int)) ? (int*)d_ws : nullptr;
    if (flag) {
        detect_layout_kernel<<<1, 256, 0, stream>>>((const unsigned int*)adj, flag);
    }
    ncn_kernel<<<n_links, 256, 0, stream>>>(links, adj, emb, out, flag, n_links);
}